// Round 21
// baseline (1970.839 us; speedup 1.0000x reference)
//
#include <hip/hip_runtime.h>
#include <hip/hip_bf16.h>

typedef __hip_bfloat16 bf16;
typedef __attribute__((ext_vector_type(8))) short bf16x8;
typedef __attribute__((ext_vector_type(4))) float f32x4;

#define MFMA_BF16 __builtin_amdgcn_mfma_f32_16x16x32_bf16
#define GLDS(src, dst) __builtin_amdgcn_global_load_lds( \
    (const __attribute__((address_space(1))) void*)(src), \
    (__attribute__((address_space(3))) void*)(dst), 16, 0, 0)

__device__ __forceinline__ float bfbits2f(short s) {
    union { unsigned u; float f; } cv;
    cv.u = (unsigned)(unsigned short)s << 16;
    return cv.f;
}
__device__ __forceinline__ short f2bfbits(float f) {
    union { bf16 h; short s; } cv;
    cv.h = __float2bfloat16(f);
    return cv.s;
}
__device__ __forceinline__ unsigned pack2bf(float a, float b) {
    union { bf16 h; unsigned short s; } ca, cb;
    ca.h = __float2bfloat16(a); cb.h = __float2bfloat16(b);
    return (unsigned)ca.s | ((unsigned)cb.s << 16);
}
// tanh-form GELU via exp2 (max abs err ~3e-3, safe vs bf16 threshold)
__device__ __forceinline__ float gelu_f(float x) {
    float inner = x * (0.7978845608f + 0.03567740814f * x * x);
    inner = fminf(inner, 40.0f);
    const float t = exp2f(inner * 2.885390082f);
    return x * (t / (t + 1.0f));
}

// ---------------------------------------------------------------------------
__global__ __launch_bounds__(256)
void transpose_cast(const float* __restrict__ src, bf16* __restrict__ dst,
                    int R, int C, size_t dst_bstride) {
    __shared__ float t[32][33];
    src += (size_t)blockIdx.z * R * C;
    dst += (size_t)blockIdx.z * dst_bstride;
    const int c0 = blockIdx.x * 32, r0 = blockIdx.y * 32;
    const int tx = threadIdx.x, ty = threadIdx.y;   // 32 x 8
#pragma unroll
    for (int i = 0; i < 32; i += 8)
        t[ty + i][tx] = src[(size_t)(r0 + ty + i) * C + c0 + tx];
    __syncthreads();
#pragma unroll
    for (int i = 0; i < 32; i += 8)
        dst[(size_t)(c0 + ty + i) * R + r0 + tx] = __float2bfloat16(t[tx][ty + i]);
}

__global__ __launch_bounds__(256)
void cast_bf16_k(const float* __restrict__ in, bf16* __restrict__ out) {
    const int i = blockIdx.x * 256 + threadIdx.x;
    const float4 v = ((const float4*)in)[i];
    union { bf16 h[4]; uint2 u; } o;
    o.h[0] = __float2bfloat16(v.x); o.h[1] = __float2bfloat16(v.y);
    o.h[2] = __float2bfloat16(v.z); o.h[3] = __float2bfloat16(v.w);
    ((uint2*)out)[i] = o.u;
}

__global__ __launch_bounds__(256)
void concat_bias_k(const float* __restrict__ bq, const float* __restrict__ bkv,
                   float* __restrict__ out) {
    const int l = blockIdx.y;
    const int i = blockIdx.x * 256 + threadIdx.x;
    out[(size_t)l * 3072 + i] = (i < 1024) ? bq[(size_t)l * 1024 + i]
                                           : bkv[(size_t)l * 2048 + i - 1024];
}

// T5 rel-pos bias collapsed to the diagonal, pre-scaled by log2(e).
__global__ __launch_bounds__(256)
void diag_k(const float* __restrict__ rel_emb, float* __restrict__ diag) {
    const int idx = blockIdx.x * 256 + threadIdx.x;   // [0,2048)
    const int h = blockIdx.y;
    int n = idx - 1023; if (n < 0) n = 0;
    int v;
    if (n < 16) {
        v = n;
    } else {
        v = 16 + (int)((logf((float)n * 0.0625f) / 2.0794415416798357f) * 16.0f);
        if (v > 31) v = 31;
    }
    diag[(size_t)h * 2048 + idx] = rel_emb[v * 16 + h] * 1.44269504088896f;
}

// ---------------------------------------------------------------------------
__device__ __forceinline__
void ln_write(float4 v, const float* g, const float* be, bf16* out,
              size_t row, int tid, float* red) {
    float s  = v.x + v.y + v.z + v.w;
    float ss = v.x * v.x + v.y * v.y + v.z * v.z + v.w * v.w;
#pragma unroll
    for (int d = 1; d < 64; d <<= 1) {
        s  += __shfl_xor(s,  d);
        ss += __shfl_xor(ss, d);
    }
    if ((tid & 63) == 0) { red[(tid >> 6) * 2] = s; red[(tid >> 6) * 2 + 1] = ss; }
    __syncthreads();
    s  = red[0] + red[2] + red[4] + red[6];
    ss = red[1] + red[3] + red[5] + red[7];
    const float mu = s * (1.0f / 1024.0f);
    const float rstd = rsqrtf(ss * (1.0f / 1024.0f) - mu * mu + 1e-5f);
    const float4 gv = ((const float4*)g)[tid];
    const float4 bv = ((const float4*)be)[tid];
    union { bf16 h[4]; uint2 u; } o;
    o.h[0] = __float2bfloat16((v.x - mu) * rstd * gv.x + bv.x);
    o.h[1] = __float2bfloat16((v.y - mu) * rstd * gv.y + bv.y);
    o.h[2] = __float2bfloat16((v.z - mu) * rstd * gv.z + bv.z);
    o.h[3] = __float2bfloat16((v.w - mu) * rstd * gv.w + bv.w);
    ((uint2*)(out + row * 1024))[tid] = o.u;
}

__global__ __launch_bounds__(256)
void layernorm_k(const float* __restrict__ x, const float* __restrict__ g,
                 const float* __restrict__ be, bf16* __restrict__ out) {
    __shared__ float red[8];
    const int row = blockIdx.x, tid = threadIdx.x;
    const float4 v = ((const float4*)(x + (size_t)row * 1024))[tid];
    ln_write(v, g, be, out, row, tid, red);
}

// combine NCH bf16 split-K partials + bias + residual -> xf, then LN -> out
template <int NCH>
__global__ __launch_bounds__(256)
void combine_ln_k(const bf16* __restrict__ part, const float* __restrict__ bias,
                  float* __restrict__ xf, const float* __restrict__ g,
                  const float* __restrict__ be, bf16* __restrict__ out) {
    __shared__ float red[8];
    const int row = blockIdx.x, tid = threadIdx.x;
    const size_t idx = (size_t)row * 256 + tid;      // uint2 index (4 elems)
    const size_t PS = (size_t)4096 * 256;            // uint2 per chunk
    float4 v = ((const float4*)bias)[tid];
    const float4 r = ((const float4*)xf)[idx];
    v.x += r.x; v.y += r.y; v.z += r.z; v.w += r.w;
#pragma unroll
    for (int c = 0; c < NCH; ++c) {
        const uint2 p = ((const uint2*)part)[c * PS + idx];
        v.x += bfbits2f((short)(p.x & 0xffff));
        v.y += bfbits2f((short)(p.x >> 16));
        v.z += bfbits2f((short)(p.y & 0xffff));
        v.w += bfbits2f((short)(p.y >> 16));
    }
    ((float4*)xf)[idx] = v;
    ln_write(v, g, be, out, row, tid, red);
}

template <int NCH>
__global__ __launch_bounds__(256)
void combine_out_k(const bf16* __restrict__ part, const float* __restrict__ bias,
                   const float* __restrict__ xf, float* __restrict__ out) {
    const int row = blockIdx.x, tid = threadIdx.x;
    const size_t idx = (size_t)row * 256 + tid;
    const size_t PS = (size_t)4096 * 256;
    float4 v = ((const float4*)bias)[tid];
    const float4 r = ((const float4*)xf)[idx];
    v.x += r.x; v.y += r.y; v.z += r.z; v.w += r.w;
#pragma unroll
    for (int c = 0; c < NCH; ++c) {
        const uint2 p = ((const uint2*)part)[c * PS + idx];
        v.x += bfbits2f((short)(p.x & 0xffff));
        v.y += bfbits2f((short)(p.x >> 16));
        v.z += bfbits2f((short)(p.y & 0xffff));
        v.w += bfbits2f((short)(p.y >> 16));
    }
    ((float4*)out)[idx] = v;
}

// ---------------------------------------------------------------------------
// GEMM 256x256, BK=64, 8 waves (2Mx4N), 2 LDS buffers, K-subtile stage units,
// counted vmcnt(4), 4 phases/tile, extra mid-phase barriers for wave
// role-split (T5). Reads strictly AFTER the vmcnt+barrier publish point.
// Optional split-K via blockIdx.z.
//   EPI 0: bf16 = acc+bias | 1: bf16 = gelu(acc+bias) | 2: bf16 partial = acc
// ---------------------------------------------------------------------------
template <int EPI>
__global__ __launch_bounds__(512)
void gemm256_k(const bf16* __restrict__ A, const bf16* __restrict__ Bt,
               const float* __restrict__ bias, void* __restrict__ outp,
               int Ncols, int Kfull, int CK) {
    __shared__ bf16 sA[2][16384];
    __shared__ bf16 sB[2][16384];
    const int tid = threadIdx.x;
    const int w = tid >> 6, l = tid & 63;
    const int wm = w >> 2, wn = w & 3;
    const int lrow = l & 15, lk = l >> 4;

    const int nx = gridDim.x;
    const int nwg = nx * gridDim.y;
    const int orig = blockIdx.y * nx + blockIdx.x;
    const int qd = nwg >> 3, rm = nwg & 7;
    const int xcd = orig & 7, loc = orig >> 3;
    const int wg = (xcd < rm ? xcd * (qd + 1) : rm * (qd + 1) + (xcd - rm) * qd) + loc;
    const int row0 = (wg / nx) * 256, col0 = (wg % nx) * 256;
    const size_t kbase = (size_t)blockIdx.z * CK;

    const int srow = tid >> 2;
    const int scol = ((((tid & 3) * 16) ^ (((srow >> 1) & 3) << 4))) >> 1;
    const bf16* gA = A  + (size_t)(row0 + srow) * Kfull + kbase + scol;
    const bf16* gB = Bt + (size_t)(col0 + srow) * Kfull + kbase + scol;
    const size_t j1 = (size_t)128 * Kfull;
    const int dst0 = tid * 8;

#define STAGE_U(mat, buf, ks, k0)                                              \
    do {                                                                       \
        GLDS(g##mat + (k0) + (ks) * 32,                                        \
             &s##mat[buf][(ks) * 8192 + dst0]);                                \
        GLDS(g##mat + j1 + (k0) + (ks) * 32,                                   \
             &s##mat[buf][(ks) * 8192 + 4096 + dst0]);                         \
    } while (0)

    int aoff[8][2], boff[4][2];
#pragma unroll
    for (int m = 0; m < 8; ++m) {
        const int ra = wm * 128 + m * 16 + lrow;
        const int sz = ((lk * 16) ^ (((ra >> 1) & 3) << 4));
#pragma unroll
        for (int ks = 0; ks < 2; ++ks) aoff[m][ks] = ks * 16384 + ra * 64 + sz;
    }
#pragma unroll
    for (int n = 0; n < 4; ++n) {
        const int rb = wn * 64 + n * 16 + lrow;
        const int sz = ((lk * 16) ^ (((rb >> 1) & 3) << 4));
#pragma unroll
        for (int ks = 0; ks < 2; ++ks) boff[n][ks] = ks * 16384 + rb * 64 + sz;
    }

    const f32x4 fz = {0.f, 0.f, 0.f, 0.f};
    f32x4 acc[8][4];
#pragma unroll
    for (int m = 0; m < 8; ++m)
#pragma unroll
        for (int n = 0; n < 4; ++n) acc[m][n] = fz;

    STAGE_U(A, 0, 0, 0); STAGE_U(B, 0, 0, 0);
    STAGE_U(A, 0, 1, 0); STAGE_U(B, 0, 1, 0);

    const int NT = CK >> 6;
    for (int t = 0; t < NT; ++t) {
        const int buf = t & 1, nb = buf ^ 1;
        const bool more = (t + 1 < NT);
        const int kn = (t + 1) << 6;
        const char* bA = (const char*)sA[buf];
        const char* bB = (const char*)sB[buf];
        bf16x8 a[4], b[4];

        // ---- publish t's k0 units; phase 0 (k0, m-lo) ----
        asm volatile("s_waitcnt vmcnt(4)" ::: "memory");
        __builtin_amdgcn_s_barrier();
        __builtin_amdgcn_sched_barrier(0);
        if (more) STAGE_U(A, nb, 0, kn);
#pragma unroll
        for (int n = 0; n < 4; ++n) b[n] = *(const bf16x8*)(bB + boff[n][0]);
#pragma unroll
        for (int m = 0; m < 4; ++m) a[m] = *(const bf16x8*)(bA + aoff[m][0]);
        __builtin_amdgcn_s_setprio(1);
#pragma unroll
        for (int m = 0; m < 4; ++m)
#pragma unroll
            for (int n = 0; n < 4; ++n)
                acc[m][n] = MFMA_BF16(b[n], a[m], acc[m][n], 0, 0, 0);
        __builtin_amdgcn_s_setprio(0);
        __builtin_amdgcn_s_barrier();     // role-split: lock phases

        // ---- phase 1 (k0, m-hi) ----
        if (more) STAGE_U(B, nb, 0, kn);
#pragma unroll
        for (int m = 0; m < 4; ++m) a[m] = *(const bf16x8*)(bA + aoff[4 + m][0]);
        __builtin_amdgcn_s_setprio(1);
#pragma unroll
        for (int m = 0; m < 4; ++m)
#pragma unroll
            for (int n = 0; n < 4; ++n)
                acc[4 + m][n] = MFMA_BF16(b[n], a[m], acc[4 + m][n], 0, 0, 0);
        __builtin_amdgcn_s_setprio(0);

        // ---- publish t's k1 units; phase 2 (k1, m-lo) ----
        if (more)
            asm volatile("s_waitcnt vmcnt(4)" ::: "memory");
        else
            asm volatile("s_waitcnt vmcnt(0)" ::: "memory");
        __builtin_amdgcn_s_barrier();
        __builtin_amdgcn_sched_barrier(0);
        if (more) STAGE_U(A, nb, 1, kn);
#pragma unroll
        for (int n = 0; n < 4; ++n) b[n] = *(const bf16x8*)(bB + boff[n][1]);
#pragma unroll
        for (int m = 0; m < 4; ++m) a[m] = *(const bf16x8*)(bA + aoff[m][1]);
        __builtin_amdgcn_s_setprio(1);
#pragma unroll
        for (int m = 0; m < 4; ++m)
#pragma unroll
            for (int n = 0; n < 4; ++n)
                acc[m][n] = MFMA_BF16(b[n], a[m], acc[m][n], 0, 0, 0);
        __builtin_amdgcn_s_setprio(0);
        __builtin_amdgcn_s_barrier();     // role-split: lock phases

        // ---- phase 3 (k1, m-hi) ----
        if (more) STAGE_U(B, nb, 1, kn);
#pragma unroll
        for (int m = 0; m < 4; ++m) a[m] = *(const bf16x8*)(bA + aoff[4 + m][1]);
        __builtin_amdgcn_s_setprio(1);
#pragma unroll
        for (int m = 0; m < 4; ++m)
#pragma unroll
            for (int n = 0; n < 4; ++n)
                acc[4 + m][n] = MFMA_BF16(b[n], a[m], acc[4 + m][n], 0, 0, 0);
        __builtin_amdgcn_s_setprio(0);
    }
#undef STAGE_U

    bf16* pout = (bf16*)outp;
    if (EPI == 2)
        pout += (size_t)blockIdx.z * ((size_t)gridDim.y * 256) * Ncols;
#pragma unroll
    for (int m = 0; m < 8; ++m) {
        const int gr = row0 + wm * 128 + m * 16 + lrow;
#pragma unroll
        for (int n = 0; n < 4; ++n) {
            const int gc0 = col0 + wn * 64 + n * 16 + lk * 4;
            float4 bb = {0.f, 0.f, 0.f, 0.f};
            if (EPI != 2) bb = *(const float4*)(bias + gc0);
            float v0 = acc[m][n][0] + bb.x, v1 = acc[m][n][1] + bb.y;
            float v2 = acc[m][n][2] + bb.z, v3 = acc[m][n][3] + bb.w;
            if (EPI == 1) {
                v0 = gelu_f(v0); v1 = gelu_f(v1); v2 = gelu_f(v2); v3 = gelu_f(v3);
            }
            uint2 pw;
            pw.x = pack2bf(v0, v1);
            pw.y = pack2bf(v2, v3);
            *(uint2*)(pout + (size_t)gr * Ncols + gc0) = pw;
        }
    }
}

// ---------------------------------------------------------------------------
// GEMM 128x128 (optional split-K): 3-buffer depth-2 pipeline.
//   EPI 0: bf16 = acc+bias | 2: f32 = acc+bias+res
//   EPI 3: bf16 partial = acc (chunk blockIdx.z)
// ---------------------------------------------------------------------------
template <int EPI>
__global__ __launch_bounds__(256)
void gemm2_k(const bf16* __restrict__ A, const bf16* __restrict__ Bt,
             const float* __restrict__ bias, const float* __restrict__ res,
             void* __restrict__ outp, int Rows, int Ncols, int Kfull, int CK) {
    __shared__ bf16 sA[3][4096];
    __shared__ bf16 sB[3][4096];
    const int tid = threadIdx.x;
    const int w = tid >> 6, l = tid & 63;
    const int wm = w >> 1, wn = w & 1;

    const int nx = gridDim.x;
    const int nwg = nx * gridDim.y;
    const int orig = blockIdx.y * nx + blockIdx.x;
    const int qd = nwg >> 3, rm = nwg & 7;
    const int xcd = orig & 7, loc = orig >> 3;
    const int wg = (xcd < rm ? xcd * (qd + 1) : rm * (qd + 1) + (xcd - rm) * qd) + loc;
    const int row0 = (wg / nx) * 128, col0 = (wg % nx) * 128;

    const int lrow = l & 15, lk = l >> 4;
    const size_t kbase = (size_t)blockIdx.z * CK;

    int rS[2], kS[2];
#pragma unroll
    for (int i = 0; i < 2; ++i) {
        const int r = (w * 2 + i) * 16 + (l >> 2);
        const int lin = (l & 3) * 16;
        const int c = lin ^ (((r >> 1) & 3) << 4);
        rS[i] = r; kS[i] = c >> 1;
    }
    const bf16* gA0 = A  + (size_t)(row0 + rS[0]) * Kfull + kbase + kS[0];
    const bf16* gA1 = A  + (size_t)(row0 + rS[1]) * Kfull + kbase + kS[1];
    const bf16* gB0 = Bt + (size_t)(col0 + rS[0]) * Kfull + kbase + kS[0];
    const bf16* gB1 = Bt + (size_t)(col0 + rS[1]) * Kfull + kbase + kS[1];
    const int dA0 = (w * 2 + 0) * 512, dA1 = (w * 2 + 1) * 512;

    const f32x4 fz = {0.f, 0.f, 0.f, 0.f};
    f32x4 acc[4][4];
#pragma unroll
    for (int m = 0; m < 4; ++m)
#pragma unroll
        for (int n = 0; n < 4; ++n) acc[m][n] = fz;

#define STAGE(buf, k0)                              \
    do {                                            \
        GLDS(gA0 + (k0), &sA[buf][dA0]);            \
        GLDS(gA1 + (k0), &sA[buf][dA1]);            \
        GLDS(gB0 + (k0), &sB[buf][dA0]);            \
        GLDS(gB1 + (k0), &sB[buf][dA1]);            \
    } while (0)

    STAGE(0, 0);
    STAGE(1, 32);

    int offA[4], offB[4];
#pragma unroll
    for (int m = 0; m < 4; ++m) {
        const int ra = wm * 64 + m * 16 + lrow;
        offA[m] = ra * 64 + ((lk * 16) ^ (((ra >> 1) & 3) << 4));
        const int rb = wn * 64 + m * 16 + lrow;
        offB[m] = rb * 64 + ((lk * 16) ^ (((rb >> 1) & 3) << 4));
    }

    const int NT = CK >> 5;
    int cur = 0, nx2 = 2;
    for (int t = 0; t < NT; ++t) {
        if (t + 1 < NT)
            asm volatile("s_waitcnt vmcnt(4)" ::: "memory");
        else
            asm volatile("s_waitcnt vmcnt(0)" ::: "memory");
        __builtin_amdgcn_s_barrier();
        __builtin_amdgcn_sched_barrier(0);

        if (t + 2 < NT) STAGE(nx2, (t + 2) << 5);

        const char* bA = (const char*)sA[cur];
        const char* bB = (const char*)sB[cur];
        bf16x8 a[4], b[4];
#pragma unroll
        for (int m = 0; m < 4; ++m) a[m] = *(const bf16x8*)(bA + offA[m]);
#pragma unroll
        for (int n = 0; n < 4; ++n) b[n] = *(const bf16x8*)(bB + offB[n]);
#pragma unroll
        for (int m = 0; m < 4; ++m)
#pragma unroll
            for (int n = 0; n < 4; ++n)
                acc[m][n] = MFMA_BF16(a[m], b[n], acc[m][n], 0, 0, 0);

        cur = (cur == 2) ? 0 : cur + 1;
        nx2 = (nx2 == 2) ? 0 : nx2 + 1;
    }
#undef STAGE

    const int erow = lk * 4;
    bf16* pout16 = (EPI == 3)
        ? (bf16*)outp + (size_t)blockIdx.z * Rows * Ncols : (bf16*)outp;
#pragma unroll
    for (int m = 0; m < 4; ++m) {
#pragma unroll
        for (int n = 0; n < 4; ++n) {
            const int gc = col0 + wn * 64 + n * 16 + lrow;
            const float bb = (EPI == 3) ? 0.f : bias[gc];
#pragma unroll
            for (int r = 0; r < 4; ++r) {
                const int gr = row0 + wm * 64 + m * 16 + erow + r;
                const size_t idx = (size_t)gr * Ncols + gc;
                float v = acc[m][n][r] + bb;
                if (EPI == 3) {
                    pout16[idx] = __float2bfloat16(v);
                } else if (EPI == 2) {
                    ((float*)outp)[idx] = v + res[idx];
                } else if (EPI == 1) {
                    ((bf16*)outp)[idx] = __float2bfloat16(gelu_f(v));
                } else {
                    ((bf16*)outp)[idx] = __float2bfloat16(v);
                }
            }
        }
    }
}

// ---------------------------------------------------------------------------
// Fused flash attention, 8 waves / 128 q-rows per block, KVBLK=64,
// double-buffered K/V shared by all waves, swapped QK^T, fixed-max exp2
// softmax, per-wave P tile.
// ---------------------------------------------------------------------------
template <int HAS_BIAS>
__global__ __launch_bounds__(512)
void attn_k(const bf16* __restrict__ Q, int qstr,
            const bf16* __restrict__ KV, int kvstr, int koff, int voff,
            bf16* __restrict__ Out, const float* __restrict__ diag,
            int Nq, int Nkv) {
    __shared__ bf16 sK[2][4096];
    __shared__ bf16 sVt[2][4096];
    __shared__ bf16 sP[8192];
    __shared__ float sdiag[2048];

    const int bz = blockIdx.z, h = blockIdx.y, q0 = blockIdx.x * 128;
    const int tid = threadIdx.x, w = tid >> 6, l = tid & 63;
    const int lrow = l & 15, lk = l >> 4;
    const int sw = (lrow & 7) << 4;
    const float c1 = 0.125f * 1.44269504088896f;

    if (HAS_BIAS) {
        ((float4*)sdiag)[tid] = ((const float4*)(diag + (size_t)h * 2048))[tid];
    }

    const int qrow = q0 + w * 16 + lrow;
    const bf16* qptr = Q + (size_t)(bz * Nq + qrow) * qstr + h * 64;
    bf16x8 aq0 = *(const bf16x8*)(qptr + lk * 8);
    bf16x8 aq1 = *(const bf16x8*)(qptr + 32 + lk * 8);
#pragma unroll
    for (int i = 0; i < 8; ++i) {
        aq0[i] = f2bfbits(bfbits2f(aq0[i]) * c1);
        aq1[i] = f2bfbits(bfbits2f(aq1[i]) * c1);
    }

    const int kr = tid >> 3, kcb = (tid & 7) * 16;
    const int vjp = (tid & 31) * 2, vf = (tid >> 5) * 4;

    const f32x4 fz = {0.f, 0.f, 0.f, 0.f};
    f32x4 o[4];
#pragma unroll
    for (int n = 0; n < 4; ++n) o[n] = fz;
    float l_lane = 0.f;

    char* sPw = (char*)sP + w * 2048;

    uint2 vr0, vr1;
#define STAGE_K(buf, j0)                                                        \
    do {                                                                        \
        const bf16* src = KV + (size_t)(bz * Nkv + (j0) + kr) * kvstr + koff    \
                          + h * 64 + ((kcb ^ ((kr & 7) << 4)) >> 1);            \
        GLDS(src, (char*)sK[buf] + tid * 16);                                   \
    } while (0)
#define LOAD_V(j0)                                                              \
    do {                                                                        \
        const bf16* vp = KV + (size_t)(bz * Nkv + (j0) + vjp) * kvstr + voff    \
                         + h * 64 + vf;                                         \
        vr0 = *(const uint2*)vp;                                                \
        vr1 = *(const uint2*)(vp + kvstr);                                      \
    } while (0)
#define WRITE_V(buf)                                                            \
    do {                                                                        \
        _Pragma("unroll")                                                       \
        for (int i = 0; i < 4; ++i) {                                           \
            const unsigned lo = ((i < 2 ? vr0.x : vr0.y) >> (16 * (i & 1)))     \
                                & 0xffffu;                                      \
            const unsigned hi = ((i < 2 ? vr1.x : vr1.y) >> (16 * (i & 1)))     \
                                & 0xffffu;                                      \
            const int byte = (((vf + i) * 128 + vjp * 2)                        \
                              ^ (((vf + i) & 7) << 4));                         \
            *(unsigned*)((char*)sVt[buf] + byte) = lo | (hi << 16);             \
        }                                                                       \
    } while (0)

    STAGE_K(0, 0);
    LOAD_V(0);
    asm volatile("s_waitcnt vmcnt(0)" ::: "memory");
    WRITE_V(0);
    __syncthreads();

    const int NT = Nkv >> 6;
    for (int t = 0; t < NT; ++t) {
        const int cb = t & 1, nb = cb ^ 1;
        const int j0 = t << 6;
        const bool more = (t + 1 < NT);

        if (more) { STAGE_K(nb, j0 + 64); LOAD_V(j0 + 64); }

        f32x4 s[4];
        __builtin_amdgcn_s_setprio(1);
#pragma unroll
        for (int jt = 0; jt < 4; ++jt) {
            const int rbase = (jt * 16 + lrow) * 128;
            const bf16x8 bk0 = *(const bf16x8*)((char*)sK[cb] + ((rbase + lk * 16) ^ sw));
            const bf16x8 bk1 = *(const bf16x8*)((char*)sK[cb] + ((rbase + 64 + lk * 16) ^ sw));
            s[jt] = MFMA_BF16(bk0, aq0, fz, 0, 0, 0);
            s[jt] = MFMA_BF16(bk1, aq1, s[jt], 0, 0, 0);
        }
        __builtin_amdgcn_s_setprio(0);

        const int dbase = q0 - j0 + 1023 + w * 16 + lrow - lk * 4;
        float ps[4][4];
        float ts0 = 0.f, ts1 = 0.f;
#pragma unroll
        for (int jt = 0; jt < 4; ++jt) {
#pragma unroll
            for (int r = 0; r < 4; ++r) {
                float v = s[jt][r] - 4.0f;
                if (HAS_BIAS) v += sdiag[dbase - jt * 16 - r];
                const float e = exp2f(v);
                ps[jt][r] = e;
                if (r & 1) ts1 += e; else ts0 += e;
            }
        }
        l_lane += ts0 + ts1;

#pragma unroll
        for (int jt = 0; jt < 4; ++jt) {
            uint2 pw;
            pw.x = pack2bf(ps[jt][0], ps[jt][1]);
            pw.y = pack2bf(ps[jt][2], ps[jt][3]);
            const int byte = lrow * 128 + ((jt * 32 + lk * 8) ^ sw);
            *(uint2*)(sPw + byte) = pw;
        }

        const bf16x8 ap0 = *(const bf16x8*)(sPw + (lrow * 128 + (lk * 16 ^ sw)));
        const bf16x8 ap1 = *(const bf16x8*)(sPw + (lrow * 128 + ((64 + lk * 16) ^ sw)));
        __builtin_amdgcn_s_setprio(1);
#pragma unroll
        for (int n = 0; n < 4; ++n) {
            const int fb = (n * 16 + lrow) * 128;
            const bf16x8 bv0 = *(const bf16x8*)((char*)sVt[cb] + ((fb + lk * 16) ^ sw));
            const bf16x8 bv1 = *(const bf16x8*)((char*)sVt[cb] + ((fb + 64 + lk * 16) ^ sw));
            o[n] = MFMA_BF16(ap0, bv0, o[n], 0, 0, 0);
            o[n] = MFMA_BF16(ap1, bv1, o[n], 0, 0, 0);
        }
        __builtin_amdgcn_s_setprio(0);

        if (more) {
            asm volatile("s_waitcnt vmcnt(0)" ::: "memory");
            WRITE_V(nb);
            __syncthreads();
        }
    }
#undef STAGE_K
#undef LOAD_V
#undef WRITE_V

    l_lane += __shfl_xor(l_lane, 16);
    l_lane += __shfl_xor(l_lane, 32);
    float inv[4];
#pragma unroll
    for (int r = 0; r < 4; ++r) inv[r] = 1.0f / __shfl(l_lane, lk * 4 + r);

#pragma unroll
    for (int n = 0; n < 4; ++n)
#pragma unroll
        for (int r = 0; r < 4; ++r) {
            const float val = o[n][r] * inv[r];
            Out[(size_t)(bz * Nq + q0 + w * 16 + lk * 4 + r) * 1024 + h * 64 + n * 16 + lrow]
                = __float2bfloat16(val);
        }
}

// ---------------------------------------------------------------------------
extern "C" void kernel_launch(void* const* d_in, const int* in_sizes, int n_in,
                              void* d_out, int out_size, void* d_ws, size_t ws_size,
                              hipStream_t stream) {
    (void)in_sizes; (void)n_in; (void)out_size; (void)ws_size;

    const float* x_in   = (const float*)d_in[0];
    const float* ctx_in = (const float*)d_in[1];
    const float* rel    = (const float*)d_in[3];
    const float* sa_wq  = (const float*)d_in[4];  const float* sa_bq  = (const float*)d_in[5];
    const float* sa_wkv = (const float*)d_in[6];  const float* sa_bkv = (const float*)d_in[7];
    const float* sa_wo  = (const float*)d_in[8];  const float* sa_bo  = (const float*)d_in[9];
    const float* sa_lng = (const float*)d_in[10]; const float* sa_lnb = (const float*)d_in[11];
    const float* ca_wq  = (const float*)d_in[12]; const float* ca_bq  = (const float*)d_in[13];
    const float* ca_wkv = (const float*)d_in[14]; const float* ca_bkv = (const float*)d_in[15];
    const float* ca_wo  = (const float*)d_in[16]; const float* ca_bo  = (const float*)d_in[17];
    const float* ca_lng = (const float*)d_in[18]; const float* ca_lnb = (const float*)d_in[19];
    const float* ff_w1  = (const float*)d_in[20]; const float* ff_b1  = (const float*)d_in[21];
    const float* ff_w2  = (const float*)d_in[22]; const float* ff_b2  = (const float*)d_in[23];
    const float* ff_lng = (const float*)d_in[24]; const float* ff_lnb = (const float*)d_in[25];

    char* ws = (char*)d_ws;
    size_t off = 0;
    auto alloc = [&](size_t bytes) {
        char* p = ws + off;
        off += (bytes + 255) & ~(size_t)255;
        return p;
    };
    const size_t DD = (size_t)1024 * 1024;

    bf16* wt_saqkv = (bf16*)alloc(6 * 3 * DD * 2);
    bf16* wt_sao   = (bf16*)alloc(6 * DD * 2);
    bf16* wt_caq   = (bf16*)alloc(6 * DD * 2);
    bf16* wt_cakv  = (bf16*)alloc(6 * 2 * DD * 2);
    bf16* wt_cao   = (bf16*)alloc(6 * DD * 2);
    bf16* wt_ff1   = (bf16*)alloc(6 * 4 * DD * 2);
    bf16* wt_ff2   = (bf16*)alloc(6 * 4 * DD * 2);
    float* sab_qkv = (float*)alloc(6 * 3072 * 4);
    float* xf      = (float*)alloc(4 * DD * 4);
    bf16* xn       = (bf16*)alloc(4 * DD * 2);
    bf16* qb       = (bf16*)alloc(4 * DD * 2);
    bf16* kvb6     = (bf16*)alloc(12 * DD * 2);
    bf16* tmpb     = (bf16*)alloc(16 * DD * 2);
    bf16* ctxb     = (bf16*)alloc(DD * 2);
    float* dgb     = (float*)alloc(16 * 2048 * 4);
    bf16* part     = (bf16*)alloc(4 * 4 * DD * 2);   // bf16 split-K partials (4 chunks)
    bf16* qkvb = tmpb + 4 * DD;

    const dim3 tpb(32, 8);
    transpose_cast<<<dim3(32, 32, 6),  tpb, 0, stream>>>(sa_wq,  wt_saqkv,      1024, 1024, 3 * DD);
    transpose_cast<<<dim3(64, 32, 6),  tpb, 0, stream>>>(sa_wkv, wt_saqkv + DD, 1024, 2048, 3 * DD);
    transpose_cast<<<dim3(32, 32, 6),  tpb, 0, stream>>>(sa_wo,  wt_sao,  1024, 1024, DD);
    transpose_cast<<<dim3(32, 32, 6),  tpb, 0, stream>>>(ca_wq,  wt_caq,  1024, 1024, DD);
    transpose_cast<<<dim3(64, 32, 6),  tpb, 0, stream>>>(ca_wkv, wt_cakv, 1024, 2048, 2 * DD);
    transpose_cast<<<dim3(32, 32, 6),  tpb, 0, stream>>>(ca_wo,  wt_cao,  1024, 1024, DD);
    transpose_cast<<<dim3(128, 32, 6), tpb, 0, stream>>>(ff_w1,  wt_ff1,  1024, 4096, 4 * DD);
    transpose_cast<<<dim3(32, 128, 6), tpb, 0, stream>>>(ff_w2,  wt_ff2,  4096, 1024, 4 * DD);
    concat_bias_k<<<dim3(12, 6), 256, 0, stream>>>(sa_bq, sa_bkv, sab_qkv);
    diag_k<<<dim3(8, 16), 256, 0, stream>>>(rel, dgb);
    cast_bf16_k<<<1024, 256, 0, stream>>>(ctx_in, ctxb);
    hipMemcpyAsync(xf, x_in, 4 * DD * sizeof(float), hipMemcpyDeviceToDevice, stream);

    // all-layer cross-attn KV projection (128² tile, 768 blocks = 3/CU)
    gemm2_k<0><<<dim3(96, 8), 256, 0, stream>>>(ctxb, wt_cakv, ca_bkv, nullptr, kvb6,
                                                1024, 12288, 1024, 1024);
    layernorm_k<<<4096, 256, 0, stream>>>(xf, sa_lng, sa_lnb, xn);

    for (int l = 0; l < 6; ++l) {
        // ---- self attention ----
        gemm2_k<0><<<dim3(24, 32), 256, 0, stream>>>(xn, wt_saqkv + l * 3 * DD,
                                                     sab_qkv + l * 3072, nullptr, qkvb,
                                                     4096, 3072, 1024, 1024);
        attn_k<1><<<dim3(8, 16, 4), 512, 0, stream>>>(qkvb, 3072, qkvb, 3072, 1024, 2048,
                                                      tmpb, dgb, 1024, 1024);
        gemm2_k<3><<<dim3(8, 32, 2), 256, 0, stream>>>(tmpb, wt_sao + l * DD, nullptr,
                                                       nullptr, part, 4096, 1024, 1024, 512);
        combine_ln_k<2><<<4096, 256, 0, stream>>>(part, sa_bo + l * 1024, xf,
                                                  ca_lng + l * 1024, ca_lnb + l * 1024, xn);
        // ---- cross attention ----
        gemm2_k<0><<<dim3(8, 32), 256, 0, stream>>>(xn, wt_caq + l * DD, ca_bq + l * 1024,
                                                    nullptr, qb, 4096, 1024, 1024, 1024);
        attn_k<0><<<dim3(8, 16, 4), 512, 0, stream>>>(qb, 1024, kvb6, 12288,
                                                      l * 2048, l * 2048 + 1024,
                                                      tmpb, nullptr, 1024, 256);
        gemm2_k<3><<<dim3(8, 32, 2), 256, 0, stream>>>(tmpb, wt_cao + l * DD, nullptr,
                                                       nullptr, part, 4096, 1024, 1024, 512);
        combine_ln_k<2><<<4096, 256, 0, stream>>>(part, ca_bo + l * 1024, xf,
                                                  ff_lng + l * 1024, ff_lnb + l * 1024, xn);
        // ---- feed-forward ----
        gemm256_k<1><<<dim3(16, 16), 512, 0, stream>>>(xn, wt_ff1 + l * 4 * DD,
                                                       ff_b1 + l * 4096, tmpb,
                                                       4096, 1024, 1024);
        gemm256_k<2><<<dim3(4, 16, 4), 512, 0, stream>>>(tmpb, wt_ff2 + l * 4 * DD,
                                                         nullptr, part,
                                                         1024, 4096, 1024);
        if (l < 5) {
            combine_ln_k<4><<<4096, 256, 0, stream>>>(part, ff_b2 + l * 1024, xf,
                                                      sa_lng + (l + 1) * 1024,
                                                      sa_lnb + (l + 1) * 1024, xn);
        } else {
            combine_out_k<4><<<4096, 256, 0, stream>>>(part, ff_b2 + l * 1024, xf, (float*)d_out);
        }
    }
}

// Round 22
// 1943.088 us; speedup vs baseline: 1.0143x; 1.0143x over previous
//
#include <hip/hip_runtime.h>
#include <hip/hip_bf16.h>

typedef __hip_bfloat16 bf16;
typedef __attribute__((ext_vector_type(8))) short bf16x8;
typedef __attribute__((ext_vector_type(4))) float f32x4;

#define MFMA_BF16 __builtin_amdgcn_mfma_f32_16x16x32_bf16
#define GLDS(src, dst) __builtin_amdgcn_global_load_lds( \
    (const __attribute__((address_space(1))) void*)(src), \
    (__attribute__((address_space(3))) void*)(dst), 16, 0, 0)

__device__ __forceinline__ float bfbits2f(short s) {
    union { unsigned u; float f; } cv;
    cv.u = (unsigned)(unsigned short)s << 16;
    return cv.f;
}
__device__ __forceinline__ short f2bfbits(float f) {
    union { bf16 h; short s; } cv;
    cv.h = __float2bfloat16(f);
    return cv.s;
}
__device__ __forceinline__ unsigned pack2bf(float a, float b) {
    union { bf16 h; unsigned short s; } ca, cb;
    ca.h = __float2bfloat16(a); cb.h = __float2bfloat16(b);
    return (unsigned)ca.s | ((unsigned)cb.s << 16);
}
// tanh-form GELU via exp2 (max abs err ~3e-3, safe vs bf16 threshold)
__device__ __forceinline__ float gelu_f(float x) {
    float inner = x * (0.7978845608f + 0.03567740814f * x * x);
    inner = fminf(inner, 40.0f);
    const float t = exp2f(inner * 2.885390082f);
    return x * (t / (t + 1.0f));
}

// ---------------------------------------------------------------------------
__global__ __launch_bounds__(256)
void transpose_cast(const float* __restrict__ src, bf16* __restrict__ dst,
                    int R, int C, size_t dst_bstride) {
    __shared__ float t[32][33];
    src += (size_t)blockIdx.z * R * C;
    dst += (size_t)blockIdx.z * dst_bstride;
    const int c0 = blockIdx.x * 32, r0 = blockIdx.y * 32;
    const int tx = threadIdx.x, ty = threadIdx.y;   // 32 x 8
#pragma unroll
    for (int i = 0; i < 32; i += 8)
        t[ty + i][tx] = src[(size_t)(r0 + ty + i) * C + c0 + tx];
    __syncthreads();
#pragma unroll
    for (int i = 0; i < 32; i += 8)
        dst[(size_t)(c0 + ty + i) * R + r0 + tx] = __float2bfloat16(t[tx][ty + i]);
}

__global__ __launch_bounds__(256)
void cast_bf16_k(const float* __restrict__ in, bf16* __restrict__ out) {
    const int i = blockIdx.x * 256 + threadIdx.x;
    const float4 v = ((const float4*)in)[i];
    union { bf16 h[4]; uint2 u; } o;
    o.h[0] = __float2bfloat16(v.x); o.h[1] = __float2bfloat16(v.y);
    o.h[2] = __float2bfloat16(v.z); o.h[3] = __float2bfloat16(v.w);
    ((uint2*)out)[i] = o.u;
}

__global__ __launch_bounds__(256)
void concat_bias_k(const float* __restrict__ bq, const float* __restrict__ bkv,
                   float* __restrict__ out) {
    const int l = blockIdx.y;
    const int i = blockIdx.x * 256 + threadIdx.x;
    out[(size_t)l * 3072 + i] = (i < 1024) ? bq[(size_t)l * 1024 + i]
                                           : bkv[(size_t)l * 2048 + i - 1024];
}

// T5 rel-pos bias collapsed to the diagonal, pre-scaled by log2(e).
__global__ __launch_bounds__(256)
void diag_k(const float* __restrict__ rel_emb, float* __restrict__ diag) {
    const int idx = blockIdx.x * 256 + threadIdx.x;   // [0,2048)
    const int h = blockIdx.y;
    int n = idx - 1023; if (n < 0) n = 0;
    int v;
    if (n < 16) {
        v = n;
    } else {
        v = 16 + (int)((logf((float)n * 0.0625f) / 2.0794415416798357f) * 16.0f);
        if (v > 31) v = 31;
    }
    diag[(size_t)h * 2048 + idx] = rel_emb[v * 16 + h] * 1.44269504088896f;
}

// ---------------------------------------------------------------------------
__device__ __forceinline__
void ln_write(float4 v, const float* g, const float* be, bf16* out,
              size_t row, int tid, float* red) {
    float s  = v.x + v.y + v.z + v.w;
    float ss = v.x * v.x + v.y * v.y + v.z * v.z + v.w * v.w;
#pragma unroll
    for (int d = 1; d < 64; d <<= 1) {
        s  += __shfl_xor(s,  d);
        ss += __shfl_xor(ss, d);
    }
    if ((tid & 63) == 0) { red[(tid >> 6) * 2] = s; red[(tid >> 6) * 2 + 1] = ss; }
    __syncthreads();
    s  = red[0] + red[2] + red[4] + red[6];
    ss = red[1] + red[3] + red[5] + red[7];
    const float mu = s * (1.0f / 1024.0f);
    const float rstd = rsqrtf(ss * (1.0f / 1024.0f) - mu * mu + 1e-5f);
    const float4 gv = ((const float4*)g)[tid];
    const float4 bv = ((const float4*)be)[tid];
    union { bf16 h[4]; uint2 u; } o;
    o.h[0] = __float2bfloat16((v.x - mu) * rstd * gv.x + bv.x);
    o.h[1] = __float2bfloat16((v.y - mu) * rstd * gv.y + bv.y);
    o.h[2] = __float2bfloat16((v.z - mu) * rstd * gv.z + bv.z);
    o.h[3] = __float2bfloat16((v.w - mu) * rstd * gv.w + bv.w);
    ((uint2*)(out + row * 1024))[tid] = o.u;
}

__global__ __launch_bounds__(256)
void layernorm_k(const float* __restrict__ x, const float* __restrict__ g,
                 const float* __restrict__ be, bf16* __restrict__ out) {
    __shared__ float red[8];
    const int row = blockIdx.x, tid = threadIdx.x;
    const float4 v = ((const float4*)(x + (size_t)row * 1024))[tid];
    ln_write(v, g, be, out, row, tid, red);
}

// combine NCH bf16 split-K partials + bias + residual -> xf, then LN -> out
template <int NCH>
__global__ __launch_bounds__(256)
void combine_ln_k(const bf16* __restrict__ part, const float* __restrict__ bias,
                  float* __restrict__ xf, const float* __restrict__ g,
                  const float* __restrict__ be, bf16* __restrict__ out) {
    __shared__ float red[8];
    const int row = blockIdx.x, tid = threadIdx.x;
    const size_t idx = (size_t)row * 256 + tid;      // uint2 index (4 elems)
    const size_t PS = (size_t)4096 * 256;            // uint2 per chunk
    float4 v = ((const float4*)bias)[tid];
    const float4 r = ((const float4*)xf)[idx];
    v.x += r.x; v.y += r.y; v.z += r.z; v.w += r.w;
#pragma unroll
    for (int c = 0; c < NCH; ++c) {
        const uint2 p = ((const uint2*)part)[c * PS + idx];
        v.x += bfbits2f((short)(p.x & 0xffff));
        v.y += bfbits2f((short)(p.x >> 16));
        v.z += bfbits2f((short)(p.y & 0xffff));
        v.w += bfbits2f((short)(p.y >> 16));
    }
    ((float4*)xf)[idx] = v;
    ln_write(v, g, be, out, row, tid, red);
}

template <int NCH>
__global__ __launch_bounds__(256)
void combine_out_k(const bf16* __restrict__ part, const float* __restrict__ bias,
                   const float* __restrict__ xf, float* __restrict__ out) {
    const int row = blockIdx.x, tid = threadIdx.x;
    const size_t idx = (size_t)row * 256 + tid;
    const size_t PS = (size_t)4096 * 256;
    float4 v = ((const float4*)bias)[tid];
    const float4 r = ((const float4*)xf)[idx];
    v.x += r.x; v.y += r.y; v.z += r.z; v.w += r.w;
#pragma unroll
    for (int c = 0; c < NCH; ++c) {
        const uint2 p = ((const uint2*)part)[c * PS + idx];
        v.x += bfbits2f((short)(p.x & 0xffff));
        v.y += bfbits2f((short)(p.x >> 16));
        v.z += bfbits2f((short)(p.y & 0xffff));
        v.w += bfbits2f((short)(p.y >> 16));
    }
    ((float4*)out)[idx] = v;
}

// ---------------------------------------------------------------------------
// GEMM 256x256, BK=64, 8 waves (2Mx4N), 2 LDS buffers, K-subtile stage units,
// counted vmcnt(4), 2 barriers/tile, 4 phases (reads strictly AFTER the
// vmcnt+barrier publish point). Optional split-K via blockIdx.z.
//   EPI 0: bf16 = acc+bias | 1: bf16 = gelu(acc+bias) | 2: bf16 partial = acc
// ---------------------------------------------------------------------------
template <int EPI>
__global__ __launch_bounds__(512)
void gemm256_k(const bf16* __restrict__ A, const bf16* __restrict__ Bt,
               const float* __restrict__ bias, void* __restrict__ outp,
               int Ncols, int Kfull, int CK) {
    __shared__ bf16 sA[2][16384];
    __shared__ bf16 sB[2][16384];
    const int tid = threadIdx.x;
    const int w = tid >> 6, l = tid & 63;
    const int wm = w >> 2, wn = w & 3;
    const int lrow = l & 15, lk = l >> 4;

    const int nx = gridDim.x;
    const int nwg = nx * gridDim.y;
    const int orig = blockIdx.y * nx + blockIdx.x;
    const int qd = nwg >> 3, rm = nwg & 7;
    const int xcd = orig & 7, loc = orig >> 3;
    const int wg = (xcd < rm ? xcd * (qd + 1) : rm * (qd + 1) + (xcd - rm) * qd) + loc;
    const int row0 = (wg / nx) * 256, col0 = (wg % nx) * 256;
    const size_t kbase = (size_t)blockIdx.z * CK;

    const int srow = tid >> 2;
    const int scol = ((((tid & 3) * 16) ^ (((srow >> 1) & 3) << 4))) >> 1;
    const bf16* gA = A  + (size_t)(row0 + srow) * Kfull + kbase + scol;
    const bf16* gB = Bt + (size_t)(col0 + srow) * Kfull + kbase + scol;
    const size_t j1 = (size_t)128 * Kfull;
    const int dst0 = tid * 8;

#define STAGE_U(mat, buf, ks, k0)                                              \
    do {                                                                       \
        GLDS(g##mat + (k0) + (ks) * 32,                                        \
             &s##mat[buf][(ks) * 8192 + dst0]);                                \
        GLDS(g##mat + j1 + (k0) + (ks) * 32,                                   \
             &s##mat[buf][(ks) * 8192 + 4096 + dst0]);                         \
    } while (0)

    int aoff[8][2], boff[4][2];
#pragma unroll
    for (int m = 0; m < 8; ++m) {
        const int ra = wm * 128 + m * 16 + lrow;
        const int sz = ((lk * 16) ^ (((ra >> 1) & 3) << 4));
#pragma unroll
        for (int ks = 0; ks < 2; ++ks) aoff[m][ks] = ks * 16384 + ra * 64 + sz;
    }
#pragma unroll
    for (int n = 0; n < 4; ++n) {
        const int rb = wn * 64 + n * 16 + lrow;
        const int sz = ((lk * 16) ^ (((rb >> 1) & 3) << 4));
#pragma unroll
        for (int ks = 0; ks < 2; ++ks) boff[n][ks] = ks * 16384 + rb * 64 + sz;
    }

    const f32x4 fz = {0.f, 0.f, 0.f, 0.f};
    f32x4 acc[8][4];
#pragma unroll
    for (int m = 0; m < 8; ++m)
#pragma unroll
        for (int n = 0; n < 4; ++n) acc[m][n] = fz;

    STAGE_U(A, 0, 0, 0); STAGE_U(B, 0, 0, 0);
    STAGE_U(A, 0, 1, 0); STAGE_U(B, 0, 1, 0);

    const int NT = CK >> 6;
    for (int t = 0; t < NT; ++t) {
        const int buf = t & 1, nb = buf ^ 1;
        const bool more = (t + 1 < NT);
        const int kn = (t + 1) << 6;
        const char* bA = (const char*)sA[buf];
        const char* bB = (const char*)sB[buf];
        bf16x8 a[4], b[4];

        asm volatile("s_waitcnt vmcnt(4)" ::: "memory");
        __builtin_amdgcn_s_barrier();
        __builtin_amdgcn_sched_barrier(0);
        if (more) STAGE_U(A, nb, 0, kn);
#pragma unroll
        for (int n = 0; n < 4; ++n) b[n] = *(const bf16x8*)(bB + boff[n][0]);
#pragma unroll
        for (int m = 0; m < 4; ++m) a[m] = *(const bf16x8*)(bA + aoff[m][0]);
        __builtin_amdgcn_s_setprio(1);
#pragma unroll
        for (int m = 0; m < 4; ++m)
#pragma unroll
            for (int n = 0; n < 4; ++n)
                acc[m][n] = MFMA_BF16(b[n], a[m], acc[m][n], 0, 0, 0);
        __builtin_amdgcn_s_setprio(0);

        if (more) STAGE_U(B, nb, 0, kn);
#pragma unroll
        for (int m = 0; m < 4; ++m) a[m] = *(const bf16x8*)(bA + aoff[4 + m][0]);
        __builtin_amdgcn_s_setprio(1);
#pragma unroll
        for (int m = 0; m < 4; ++m)
#pragma unroll
            for (int n = 0; n < 4; ++n)
                acc[4 + m][n] = MFMA_BF16(b[n], a[m], acc[4 + m][n], 0, 0, 0);
        __builtin_amdgcn_s_setprio(0);

        if (more)
            asm volatile("s_waitcnt vmcnt(4)" ::: "memory");
        else
            asm volatile("s_waitcnt vmcnt(0)" ::: "memory");
        __builtin_amdgcn_s_barrier();
        __builtin_amdgcn_sched_barrier(0);
        if (more) STAGE_U(A, nb, 1, kn);
#pragma unroll
        for (int n = 0; n < 4; ++n) b[n] = *(const bf16x8*)(bB + boff[n][1]);
#pragma unroll
        for (int m = 0; m < 4; ++m) a[m] = *(const bf16x8*)(bA + aoff[m][1]);
        __builtin_amdgcn_s_setprio(1);
#pragma unroll
        for (int m = 0; m < 4; ++m)
#pragma unroll
            for (int n = 0; n < 4; ++n)
                acc[m][n] = MFMA_BF16(b[n], a[m], acc[m][n], 0, 0, 0);
        __builtin_amdgcn_s_setprio(0);

        if (more) STAGE_U(B, nb, 1, kn);
#pragma unroll
        for (int m = 0; m < 4; ++m) a[m] = *(const bf16x8*)(bA + aoff[4 + m][1]);
        __builtin_amdgcn_s_setprio(1);
#pragma unroll
        for (int m = 0; m < 4; ++m)
#pragma unroll
            for (int n = 0; n < 4; ++n)
                acc[4 + m][n] = MFMA_BF16(b[n], a[m], acc[4 + m][n], 0, 0, 0);
        __builtin_amdgcn_s_setprio(0);
    }
#undef STAGE_U

    bf16* pout = (bf16*)outp;
    if (EPI == 2)
        pout += (size_t)blockIdx.z * ((size_t)gridDim.y * 256) * Ncols;
#pragma unroll
    for (int m = 0; m < 8; ++m) {
        const int gr = row0 + wm * 128 + m * 16 + lrow;
#pragma unroll
        for (int n = 0; n < 4; ++n) {
            const int gc0 = col0 + wn * 64 + n * 16 + lk * 4;
            float4 bb = {0.f, 0.f, 0.f, 0.f};
            if (EPI != 2) bb = *(const float4*)(bias + gc0);
            float v0 = acc[m][n][0] + bb.x, v1 = acc[m][n][1] + bb.y;
            float v2 = acc[m][n][2] + bb.z, v3 = acc[m][n][3] + bb.w;
            if (EPI == 1) {
                v0 = gelu_f(v0); v1 = gelu_f(v1); v2 = gelu_f(v2); v3 = gelu_f(v3);
            }
            uint2 pw;
            pw.x = pack2bf(v0, v1);
            pw.y = pack2bf(v2, v3);
            *(uint2*)(pout + (size_t)gr * Ncols + gc0) = pw;
        }
    }
}

// ---------------------------------------------------------------------------
// GEMM 128x128 (optional split-K): 3-buffer depth-2 pipeline.
//   EPI 0: bf16 = acc+bias | 2: f32 = acc+bias+res
//   EPI 3: bf16 partial = acc (chunk blockIdx.z)
// ---------------------------------------------------------------------------
template <int EPI>
__global__ __launch_bounds__(256)
void gemm2_k(const bf16* __restrict__ A, const bf16* __restrict__ Bt,
             const float* __restrict__ bias, const float* __restrict__ res,
             void* __restrict__ outp, int Rows, int Ncols, int Kfull, int CK) {
    __shared__ bf16 sA[3][4096];
    __shared__ bf16 sB[3][4096];
    const int tid = threadIdx.x;
    const int w = tid >> 6, l = tid & 63;
    const int wm = w >> 1, wn = w & 1;

    const int nx = gridDim.x;
    const int nwg = nx * gridDim.y;
    const int orig = blockIdx.y * nx + blockIdx.x;
    const int qd = nwg >> 3, rm = nwg & 7;
    const int xcd = orig & 7, loc = orig >> 3;
    const int wg = (xcd < rm ? xcd * (qd + 1) : rm * (qd + 1) + (xcd - rm) * qd) + loc;
    const int row0 = (wg / nx) * 128, col0 = (wg % nx) * 128;

    const int lrow = l & 15, lk = l >> 4;
    const size_t kbase = (size_t)blockIdx.z * CK;

    int rS[2], kS[2];
#pragma unroll
    for (int i = 0; i < 2; ++i) {
        const int r = (w * 2 + i) * 16 + (l >> 2);
        const int lin = (l & 3) * 16;
        const int c = lin ^ (((r >> 1) & 3) << 4);
        rS[i] = r; kS[i] = c >> 1;
    }
    const bf16* gA0 = A  + (size_t)(row0 + rS[0]) * Kfull + kbase + kS[0];
    const bf16* gA1 = A  + (size_t)(row0 + rS[1]) * Kfull + kbase + kS[1];
    const bf16* gB0 = Bt + (size_t)(col0 + rS[0]) * Kfull + kbase + kS[0];
    const bf16* gB1 = Bt + (size_t)(col0 + rS[1]) * Kfull + kbase + kS[1];
    const int dA0 = (w * 2 + 0) * 512, dA1 = (w * 2 + 1) * 512;

    const f32x4 fz = {0.f, 0.f, 0.f, 0.f};
    f32x4 acc[4][4];
#pragma unroll
    for (int m = 0; m < 4; ++m)
#pragma unroll
        for (int n = 0; n < 4; ++n) acc[m][n] = fz;

#define STAGE(buf, k0)                              \
    do {                                            \
        GLDS(gA0 + (k0), &sA[buf][dA0]);            \
        GLDS(gA1 + (k0), &sA[buf][dA1]);            \
        GLDS(gB0 + (k0), &sB[buf][dA0]);            \
        GLDS(gB1 + (k0), &sB[buf][dA1]);            \
    } while (0)

    STAGE(0, 0);
    STAGE(1, 32);

    int offA[4], offB[4];
#pragma unroll
    for (int m = 0; m < 4; ++m) {
        const int ra = wm * 64 + m * 16 + lrow;
        offA[m] = ra * 64 + ((lk * 16) ^ (((ra >> 1) & 3) << 4));
        const int rb = wn * 64 + m * 16 + lrow;
        offB[m] = rb * 64 + ((lk * 16) ^ (((rb >> 1) & 3) << 4));
    }

    const int NT = CK >> 5;
    int cur = 0, nx2 = 2;
    for (int t = 0; t < NT; ++t) {
        if (t + 1 < NT)
            asm volatile("s_waitcnt vmcnt(4)" ::: "memory");
        else
            asm volatile("s_waitcnt vmcnt(0)" ::: "memory");
        __builtin_amdgcn_s_barrier();
        __builtin_amdgcn_sched_barrier(0);

        if (t + 2 < NT) STAGE(nx2, (t + 2) << 5);

        const char* bA = (const char*)sA[cur];
        const char* bB = (const char*)sB[cur];
        bf16x8 a[4], b[4];
#pragma unroll
        for (int m = 0; m < 4; ++m) a[m] = *(const bf16x8*)(bA + offA[m]);
#pragma unroll
        for (int n = 0; n < 4; ++n) b[n] = *(const bf16x8*)(bB + offB[n]);
#pragma unroll
        for (int m = 0; m < 4; ++m)
#pragma unroll
            for (int n = 0; n < 4; ++n)
                acc[m][n] = MFMA_BF16(a[m], b[n], acc[m][n], 0, 0, 0);

        cur = (cur == 2) ? 0 : cur + 1;
        nx2 = (nx2 == 2) ? 0 : nx2 + 1;
    }
#undef STAGE

    const int erow = lk * 4;
    bf16* pout16 = (EPI == 3)
        ? (bf16*)outp + (size_t)blockIdx.z * Rows * Ncols : (bf16*)outp;
#pragma unroll
    for (int m = 0; m < 4; ++m) {
#pragma unroll
        for (int n = 0; n < 4; ++n) {
            const int gc = col0 + wn * 64 + n * 16 + lrow;
            const float bb = (EPI == 3) ? 0.f : bias[gc];
#pragma unroll
            for (int r = 0; r < 4; ++r) {
                const int gr = row0 + wm * 64 + m * 16 + erow + r;
                const size_t idx = (size_t)gr * Ncols + gc;
                float v = acc[m][n][r] + bb;
                if (EPI == 3) {
                    pout16[idx] = __float2bfloat16(v);
                } else if (EPI == 2) {
                    ((float*)outp)[idx] = v + res[idx];
                } else if (EPI == 1) {
                    ((bf16*)outp)[idx] = __float2bfloat16(gelu_f(v));
                } else {
                    ((bf16*)outp)[idx] = __float2bfloat16(v);
                }
            }
        }
    }
}

// ---------------------------------------------------------------------------
// Fused flash attention, 8 waves / 128 q-rows per block, KVBLK=64,
// double-buffered K/V shared by all waves, swapped QK^T, fixed-max exp2
// softmax, per-wave P tile.
// ---------------------------------------------------------------------------
template <int HAS_BIAS>
__global__ __launch_bounds__(512)
void attn_k(const bf16* __restrict__ Q, int qstr,
            const bf16* __restrict__ KV, int kvstr, int koff, int voff,
            bf16* __restrict__ Out, const float* __restrict__ diag,
            int Nq, int Nkv) {
    __shared__ bf16 sK[2][4096];
    __shared__ bf16 sVt[2][4096];
    __shared__ bf16 sP[8192];
    __shared__ float sdiag[2048];

    const int bz = blockIdx.z, h = blockIdx.y, q0 = blockIdx.x * 128;
    const int tid = threadIdx.x, w = tid >> 6, l = tid & 63;
    const int lrow = l & 15, lk = l >> 4;
    const int sw = (lrow & 7) << 4;
    const float c1 = 0.125f * 1.44269504088896f;

    if (HAS_BIAS) {
        ((float4*)sdiag)[tid] = ((const float4*)(diag + (size_t)h * 2048))[tid];
    }

    const int qrow = q0 + w * 16 + lrow;
    const bf16* qptr = Q + (size_t)(bz * Nq + qrow) * qstr + h * 64;
    bf16x8 aq0 = *(const bf16x8*)(qptr + lk * 8);
    bf16x8 aq1 = *(const bf16x8*)(qptr + 32 + lk * 8);
#pragma unroll
    for (int i = 0; i < 8; ++i) {
        aq0[i] = f2bfbits(bfbits2f(aq0[i]) * c1);
        aq1[i] = f2bfbits(bfbits2f(aq1[i]) * c1);
    }

    const int kr = tid >> 3, kcb = (tid & 7) * 16;
    const int vjp = (tid & 31) * 2, vf = (tid >> 5) * 4;

    const f32x4 fz = {0.f, 0.f, 0.f, 0.f};
    f32x4 o[4];
#pragma unroll
    for (int n = 0; n < 4; ++n) o[n] = fz;
    float l_lane = 0.f;

    char* sPw = (char*)sP + w * 2048;

    uint2 vr0, vr1;
#define STAGE_K(buf, j0)                                                        \
    do {                                                                        \
        const bf16* src = KV + (size_t)(bz * Nkv + (j0) + kr) * kvstr + koff    \
                          + h * 64 + ((kcb ^ ((kr & 7) << 4)) >> 1);            \
        GLDS(src, (char*)sK[buf] + tid * 16);                                   \
    } while (0)
#define LOAD_V(j0)                                                              \
    do {                                                                        \
        const bf16* vp = KV + (size_t)(bz * Nkv + (j0) + vjp) * kvstr + voff    \
                         + h * 64 + vf;                                         \
        vr0 = *(const uint2*)vp;                                                \
        vr1 = *(const uint2*)(vp + kvstr);                                      \
    } while (0)
#define WRITE_V(buf)                                                            \
    do {                                                                        \
        _Pragma("unroll")                                                       \
        for (int i = 0; i < 4; ++i) {                                           \
            const unsigned lo = ((i < 2 ? vr0.x : vr0.y) >> (16 * (i & 1)))     \
                                & 0xffffu;                                      \
            const unsigned hi = ((i < 2 ? vr1.x : vr1.y) >> (16 * (i & 1)))     \
                                & 0xffffu;                                      \
            const int byte = (((vf + i) * 128 + vjp * 2)                        \
                              ^ (((vf + i) & 7) << 4));                         \
            *(unsigned*)((char*)sVt[buf] + byte) = lo | (hi << 16);             \
        }                                                                       \
    } while (0)

    STAGE_K(0, 0);
    LOAD_V(0);
    asm volatile("s_waitcnt vmcnt(0)" ::: "memory");
    WRITE_V(0);
    __syncthreads();

    const int NT = Nkv >> 6;
    for (int t = 0; t < NT; ++t) {
        const int cb = t & 1, nb = cb ^ 1;
        const int j0 = t << 6;
        const bool more = (t + 1 < NT);

        if (more) { STAGE_K(nb, j0 + 64); LOAD_V(j0 + 64); }

        f32x4 s[4];
        __builtin_amdgcn_s_setprio(1);
#pragma unroll
        for (int jt = 0; jt < 4; ++jt) {
            const int rbase = (jt * 16 + lrow) * 128;
            const bf16x8 bk0 = *(const bf16x8*)((char*)sK[cb] + ((rbase + lk * 16) ^ sw));
            const bf16x8 bk1 = *(const bf16x8*)((char*)sK[cb] + ((rbase + 64 + lk * 16) ^ sw));
            s[jt] = MFMA_BF16(bk0, aq0, fz, 0, 0, 0);
            s[jt] = MFMA_BF16(bk1, aq1, s[jt], 0, 0, 0);
        }
        __builtin_amdgcn_s_setprio(0);

        const int dbase = q0 - j0 + 1023 + w * 16 + lrow - lk * 4;
        float ps[4][4];
        float ts0 = 0.f, ts1 = 0.f;
#pragma unroll
        for (int jt = 0; jt < 4; ++jt) {
#pragma unroll
            for (int r = 0; r < 4; ++r) {
                float v = s[jt][r] - 4.0f;
                if (HAS_BIAS) v += sdiag[dbase - jt * 16 - r];
                const float e = exp2f(v);
                ps[jt][r] = e;
                if (r & 1) ts1 += e; else ts0 += e;
            }
        }
        l_lane += ts0 + ts1;

#pragma unroll
        for (int jt = 0; jt < 4; ++jt) {
            uint2 pw;
            pw.x = pack2bf(ps[jt][0], ps[jt][1]);
            pw.y = pack2bf(ps[jt][2], ps[jt][3]);
            const int byte = lrow * 128 + ((jt * 32 + lk * 8) ^ sw);
            *(uint2*)(sPw + byte) = pw;
        }

        const bf16x8 ap0 = *(const bf16x8*)(sPw + (lrow * 128 + (lk * 16 ^ sw)));
        const bf16x8 ap1 = *(const bf16x8*)(sPw + (lrow * 128 + ((64 + lk * 16) ^ sw)));
        __builtin_amdgcn_s_setprio(1);
#pragma unroll
        for (int n = 0; n < 4; ++n) {
            const int fb = (n * 16 + lrow) * 128;
            const bf16x8 bv0 = *(const bf16x8*)((char*)sVt[cb] + ((fb + lk * 16) ^ sw));
            const bf16x8 bv1 = *(const bf16x8*)((char*)sVt[cb] + ((fb + 64 + lk * 16) ^ sw));
            o[n] = MFMA_BF16(ap0, bv0, o[n], 0, 0, 0);
            o[n] = MFMA_BF16(ap1, bv1, o[n], 0, 0, 0);
        }
        __builtin_amdgcn_s_setprio(0);

        if (more) {
            asm volatile("s_waitcnt vmcnt(0)" ::: "memory");
            WRITE_V(nb);
            __syncthreads();
        }
    }
#undef STAGE_K
#undef LOAD_V
#undef WRITE_V

    l_lane += __shfl_xor(l_lane, 16);
    l_lane += __shfl_xor(l_lane, 32);
    float inv[4];
#pragma unroll
    for (int r = 0; r < 4; ++r) inv[r] = 1.0f / __shfl(l_lane, lk * 4 + r);

#pragma unroll
    for (int n = 0; n < 4; ++n)
#pragma unroll
        for (int r = 0; r < 4; ++r) {
            const float val = o[n][r] * inv[r];
            Out[(size_t)(bz * Nq + q0 + w * 16 + lk * 4 + r) * 1024 + h * 64 + n * 16 + lrow]
                = __float2bfloat16(val);
        }
}

// ---------------------------------------------------------------------------
extern "C" void kernel_launch(void* const* d_in, const int* in_sizes, int n_in,
                              void* d_out, int out_size, void* d_ws, size_t ws_size,
                              hipStream_t stream) {
    (void)in_sizes; (void)n_in; (void)out_size; (void)ws_size;

    const float* x_in   = (const float*)d_in[0];
    const float* ctx_in = (const float*)d_in[1];
    const float* rel    = (const float*)d_in[3];
    const float* sa_wq  = (const float*)d_in[4];  const float* sa_bq  = (const float*)d_in[5];
    const float* sa_wkv = (const float*)d_in[6];  const float* sa_bkv = (const float*)d_in[7];
    const float* sa_wo  = (const float*)d_in[8];  const float* sa_bo  = (const float*)d_in[9];
    const float* sa_lng = (const float*)d_in[10]; const float* sa_lnb = (const float*)d_in[11];
    const float* ca_wq  = (const float*)d_in[12]; const float* ca_bq  = (const float*)d_in[13];
    const float* ca_wkv = (const float*)d_in[14]; const float* ca_bkv = (const float*)d_in[15];
    const float* ca_wo  = (const float*)d_in[16]; const float* ca_bo  = (const float*)d_in[17];
    const float* ca_lng = (const float*)d_in[18]; const float* ca_lnb = (const float*)d_in[19];
    const float* ff_w1  = (const float*)d_in[20]; const float* ff_b1  = (const float*)d_in[21];
    const float* ff_w2  = (const float*)d_in[22]; const float* ff_b2  = (const float*)d_in[23];
    const float* ff_lng = (const float*)d_in[24]; const float* ff_lnb = (const float*)d_in[25];

    char* ws = (char*)d_ws;
    size_t off = 0;
    auto alloc = [&](size_t bytes) {
        char* p = ws + off;
        off += (bytes + 255) & ~(size_t)255;
        return p;
    };
    const size_t DD = (size_t)1024 * 1024;

    bf16* wt_saqkv = (bf16*)alloc(6 * 3 * DD * 2);
    bf16* wt_sao   = (bf16*)alloc(6 * DD * 2);
    bf16* wt_caq   = (bf16*)alloc(6 * DD * 2);
    bf16* wt_cakv  = (bf16*)alloc(6 * 2 * DD * 2);
    bf16* wt_cao   = (bf16*)alloc(6 * DD * 2);
    bf16* wt_ff1   = (bf16*)alloc(6 * 4 * DD * 2);
    bf16* wt_ff2   = (bf16*)alloc(6 * 4 * DD * 2);
    float* sab_qkv = (float*)alloc(6 * 3072 * 4);
    float* xf      = (float*)alloc(4 * DD * 4);
    bf16* xn       = (bf16*)alloc(4 * DD * 2);
    bf16* qb       = (bf16*)alloc(4 * DD * 2);
    bf16* kvb6     = (bf16*)alloc(12 * DD * 2);
    bf16* tmpb     = (bf16*)alloc(16 * DD * 2);
    bf16* ctxb     = (bf16*)alloc(DD * 2);
    float* dgb     = (float*)alloc(16 * 2048 * 4);
    bf16* part     = (bf16*)alloc(4 * 4 * DD * 2);   // bf16 split-K partials (4 chunks)
    bf16* qkvb = tmpb + 4 * DD;

    const dim3 tpb(32, 8);
    transpose_cast<<<dim3(32, 32, 6),  tpb, 0, stream>>>(sa_wq,  wt_saqkv,      1024, 1024, 3 * DD);
    transpose_cast<<<dim3(64, 32, 6),  tpb, 0, stream>>>(sa_wkv, wt_saqkv + DD, 1024, 2048, 3 * DD);
    transpose_cast<<<dim3(32, 32, 6),  tpb, 0, stream>>>(sa_wo,  wt_sao,  1024, 1024, DD);
    transpose_cast<<<dim3(32, 32, 6),  tpb, 0, stream>>>(ca_wq,  wt_caq,  1024, 1024, DD);
    transpose_cast<<<dim3(64, 32, 6),  tpb, 0, stream>>>(ca_wkv, wt_cakv, 1024, 2048, 2 * DD);
    transpose_cast<<<dim3(32, 32, 6),  tpb, 0, stream>>>(ca_wo,  wt_cao,  1024, 1024, DD);
    transpose_cast<<<dim3(128, 32, 6), tpb, 0, stream>>>(ff_w1,  wt_ff1,  1024, 4096, 4 * DD);
    transpose_cast<<<dim3(32, 128, 6), tpb, 0, stream>>>(ff_w2,  wt_ff2,  4096, 1024, 4 * DD);
    concat_bias_k<<<dim3(12, 6), 256, 0, stream>>>(sa_bq, sa_bkv, sab_qkv);
    diag_k<<<dim3(8, 16), 256, 0, stream>>>(rel, dgb);
    cast_bf16_k<<<1024, 256, 0, stream>>>(ctx_in, ctxb);
    hipMemcpyAsync(xf, x_in, 4 * DD * sizeof(float), hipMemcpyDeviceToDevice, stream);

    // all-layer cross-attn KV projection (128² tile, 768 blocks = 3/CU)
    gemm2_k<0><<<dim3(96, 8), 256, 0, stream>>>(ctxb, wt_cakv, ca_bkv, nullptr, kvb6,
                                                1024, 12288, 1024, 1024);
    layernorm_k<<<4096, 256, 0, stream>>>(xf, sa_lng, sa_lnb, xn);

    for (int l = 0; l < 6; ++l) {
        // ---- self attention ----
        gemm2_k<0><<<dim3(24, 32), 256, 0, stream>>>(xn, wt_saqkv + l * 3 * DD,
                                                     sab_qkv + l * 3072, nullptr, qkvb,
                                                     4096, 3072, 1024, 1024);
        attn_k<1><<<dim3(8, 16, 4), 512, 0, stream>>>(qkvb, 3072, qkvb, 3072, 1024, 2048,
                                                      tmpb, dgb, 1024, 1024);
        gemm2_k<3><<<dim3(8, 32, 2), 256, 0, stream>>>(tmpb, wt_sao + l * DD, nullptr,
                                                       nullptr, part, 4096, 1024, 1024, 512);
        combine_ln_k<2><<<4096, 256, 0, stream>>>(part, sa_bo + l * 1024, xf,
                                                  ca_lng + l * 1024, ca_lnb + l * 1024, xn);
        // ---- cross attention ----
        gemm2_k<0><<<dim3(8, 32), 256, 0, stream>>>(xn, wt_caq + l * DD, ca_bq + l * 1024,
                                                    nullptr, qb, 4096, 1024, 1024, 1024);
        attn_k<0><<<dim3(8, 16, 4), 512, 0, stream>>>(qb, 1024, kvb6, 12288,
                                                      l * 2048, l * 2048 + 1024,
                                                      tmpb, nullptr, 1024, 256);
        gemm2_k<3><<<dim3(8, 32, 2), 256, 0, stream>>>(tmpb, wt_cao + l * DD, nullptr,
                                                       nullptr, part, 4096, 1024, 1024, 512);
        combine_ln_k<2><<<4096, 256, 0, stream>>>(part, ca_bo + l * 1024, xf,
                                                  ff_lng + l * 1024, ff_lnb + l * 1024, xn);
        // ---- feed-forward ----
        gemm256_k<1><<<dim3(16, 16), 512, 0, stream>>>(xn, wt_ff1 + l * 4 * DD,
                                                       ff_b1 + l * 4096, tmpb,
                                                       4096, 1024, 1024);
        gemm256_k<2><<<dim3(4, 16, 4), 512, 0, stream>>>(tmpb, wt_ff2 + l * 4 * DD,
                                                         nullptr, part,
                                                         1024, 4096, 1024);
        if (l < 5) {
            combine_ln_k<4><<<4096, 256, 0, stream>>>(part, ff_b2 + l * 1024, xf,
                                                      sa_lng + (l + 1) * 1024,
                                                      sa_lnb + (l + 1) * 1024, xn);
        } else {
            combine_out_k<4><<<4096, 256, 0, stream>>>(part, ff_b2 + l * 1024, xf, (float*)d_out);
        }
    }
}